// Round 9
// baseline (13343.935 us; speedup 1.0000x reference)
//
#include <hip/hip_runtime.h>
#include <hip/hip_bf16.h>
#include <stdint.h>

typedef float f32x4 __attribute__((ext_vector_type(4)));
typedef short bf16x8 __attribute__((ext_vector_type(8)));
typedef int   i32x4  __attribute__((ext_vector_type(4)));
typedef unsigned int u32x4 __attribute__((ext_vector_type(4)));

#define DEVINL static __device__ __forceinline__

// ---------------- problem dims ----------------
constexpr int BATCH = 256, SEQ = 512, IDIM = 512, HDIM = 512;
constexpr int NG = 8, WC = 32, RPG = 32, CPW = 16;

// ---------------- LDS map (bytes) ----------------
constexpr int WGS_OFF = 0;        // Wg stripe [32 cols][1024 k] bf16 (64KB), XOR-swizzled
constexpr int WHS_OFF = 65536;    // Wh stripe [16 cols][1024 k] bf16 (32KB)
constexpr int WO1_OFF = 98304;    // Wo1 stripe [16 cols][512 k] bf16 (16KB, cols 8..15 zero)
constexpr int XPOSE_OFF = 114688; // 32 rows x 48B repack buffer (1536B)
constexpr int SMEM_BYTES = XPOSE_OFF + 32 * 48;   // 116224

// ---------------- ws map (bytes) ----------------
// flags per group (512B region): fA u32[32] at +0, fB u32[32] at +256
constexpr size_t WS_ZERO = 4096;              // flag arrays (memset each call)
constexpr size_t HBF_OFF  = 8192;             // bf16 h   [256][512] (256KB), no init needed
constexpr size_t RHBF_OFF = HBF_OFF + 262144; // bf16 r*h [256][512] (256KB), no init needed
constexpr size_t WS_NEEDED = RHBF_OFF + 262144;

DEVINL short f2bf(float f) {
  uint32_t u = __float_as_uint(f);
  u += 0x7FFFu + ((u >> 16) & 1u);   // RNE
  return (short)(u >> 16);
}
DEVINL uint32_t cvtpk(float lo, float hi) {   // 2 bf16 in one instr (RNE)
  uint32_t r;
  asm("v_cvt_pk_bf16_f32 %0, %1, %2" : "=v"(r) : "v"(lo), "v"(hi));
  return r;
}
DEVINL int wgs_off(int c, int k) { return WGS_OFF + c * 2048 + ((k * 2) ^ ((c & 7) << 4)); }
DEVINL int whs_off(int c, int k) { return WHS_OFF + c * 2048 + ((k * 2) ^ ((c & 7) << 4)); }
DEVINL int wo1_off(int c, int k) { return WO1_OFF + c * 1024 + ((k * 2) ^ ((c & 7) << 4)); }
DEVINL float sigm(float v) { return 1.f / (1.f + __expf(-v)); }
DEVINL bf16x8 asbf(i32x4 v) { return __builtin_bit_cast(bf16x8, v); }

// ---------------- flag / exchange primitives (agent scope: sc1) ----------------
DEVINL void flag_pub(uint32_t* p, uint32_t v) {
  asm volatile("s_waitcnt vmcnt(0) lgkmcnt(0)\n\tglobal_store_dword %0, %1, off sc1"
               :: "v"(p), "v"(v) : "memory");
}
// poll own group's 32-slot region (2 lanes/slot). Throttled + bounded.
DEVINL void poll32(const uint32_t* base, uint32_t target) {
  const uint32_t* p = base + (threadIdx.x & 31);
  int iter = 0;
  for (;;) {
    uint32_t v;
    asm volatile("global_load_dword %0, %1, off sc1\n\ts_waitcnt vmcnt(0)"
                 : "=v"(v) : "v"(p) : "memory");
    if (__all((int)(v >= target))) break;
    if (++iter > 20000) break;           // bounded: pathology -> fast fail, not timeout
    __builtin_amdgcn_s_sleep(1);         // throttle the fabric read-storm
  }
  __builtin_amdgcn_sched_barrier(0);
}
// repack 32x16 bf16 tile (both M-tiles) through LDS -> one dwordx4/lane store
DEVINL void publish32x16(char* smem, short* dst, int rowbase, int colbase,
                         int lane, const float* v0, const float* v1) {
  const int q = lane >> 4, lc = lane & 15;
#pragma unroll
  for (int ri = 0; ri < 4; ++ri) {
    *(short*)(smem + XPOSE_OFF + (q * 4 + ri) * 48 + lc * 2)      = f2bf(v0[ri]);
    *(short*)(smem + XPOSE_OFF + (16 + q * 4 + ri) * 48 + lc * 2) = f2bf(v1[ri]);
  }
  asm volatile("s_waitcnt lgkmcnt(0)" ::: "memory");
  __builtin_amdgcn_sched_barrier(0);
  const int rl = lane >> 1, half = lane & 1;
  i32x4 d = *(const i32x4*)(smem + XPOSE_OFF + rl * 48 + half * 16);
  short* gp = dst + (size_t)(rowbase + rl) * HDIM + colbase + half * 8;
  asm volatile("global_store_dwordx4 %0, %1, off sc1" :: "v"(gp), "v"(d) : "memory");
}
#define GLD16NF(dst, ptr, imm) \
  asm volatile("global_load_dwordx4 %0, %1, off offset:" imm " sc1" : "=v"(dst) : "v"(ptr))
#define GLD_BATCH16(arr, ptr) do { \
  GLD16NF(arr[0],  ptr, "0");   GLD16NF(arr[1],  ptr, "64");  \
  GLD16NF(arr[2],  ptr, "128"); GLD16NF(arr[3],  ptr, "192"); \
  GLD16NF(arr[4],  ptr, "256"); GLD16NF(arr[5],  ptr, "320"); \
  GLD16NF(arr[6],  ptr, "384"); GLD16NF(arr[7],  ptr, "448"); \
  GLD16NF(arr[8],  ptr, "512"); GLD16NF(arr[9],  ptr, "576"); \
  GLD16NF(arr[10], ptr, "640"); GLD16NF(arr[11], ptr, "704"); \
  GLD16NF(arr[12], ptr, "768"); GLD16NF(arr[13], ptr, "832"); \
  GLD16NF(arr[14], ptr, "896"); GLD16NF(arr[15], ptr, "960"); \
} while (0)
#define GLD_FENCE() do { \
  asm volatile("s_waitcnt vmcnt(0)" ::: "memory"); \
  __builtin_amdgcn_sched_barrier(0); \
} while (0)

#define MFMA(a, b, c) __builtin_amdgcn_mfma_f32_16x16x32_bf16((a), (b), (c), 0, 0, 0)
#define LDB(off) (*(const bf16x8*)(smem + (off)))

__global__ void __launch_bounds__(256, 1) init_ys_kernel(float* out, const float* bo2) {
  int i = blockIdx.x * 256 + threadIdx.x;
  if (i < BATCH * SEQ) out[i] = bo2[0];
}

__global__ void __launch_bounds__(64, 1) gru_persist(
    const float* __restrict__ x,  const float* __restrict__ Wg, const float* __restrict__ bg,
    const float* __restrict__ Wh, const float* __restrict__ bh,
    const float* __restrict__ Wo1,const float* __restrict__ bo1,
    const float* __restrict__ Wo2,const float* __restrict__ bo2,
    float* __restrict__ out, char* __restrict__ ws)
{
  extern __shared__ char smem[];
  const int bid  = blockIdx.x;
  const int gi   = bid & 7;        // group; bid&7 keeps group's x rows on one XCD L2 (perf-only)
  const int j    = bid >> 3;       // 0..31 within group
  const int tid  = threadIdx.x;
  const int lane = tid & 63;
  const int rowbase = gi * RPG;
  const int colbase = j * CPW;

  short* hbf  = (short*)(ws + HBF_OFF);
  short* rhbf = (short*)(ws + RHBF_OFF);
  uint32_t* fA = (uint32_t*)(ws + (size_t)gi * 512);
  uint32_t* fB = (uint32_t*)(ws + (size_t)gi * 512 + 256);
  uint32_t* myA = fA + j;
  uint32_t* myB = fB + j;

  // ---------------- init: weights -> LDS (64 threads, one-time) ----------------
  for (int it = 0; it < 512; ++it) {
    int idx = it * 64 + tid;
    int cc = idx & 31, k = idx >> 5;
    int cg = (cc < 16) ? (colbase + cc) : (512 + colbase + (cc - 16));
    *(short*)(smem + wgs_off(cc, k)) = f2bf(Wg[(size_t)k * 1024 + cg]);
  }
  for (int it = 0; it < 256; ++it) {
    int idx = it * 64 + tid;
    int cc = idx & 15, k = idx >> 4;
    *(short*)(smem + whs_off(cc, k)) = f2bf(Wh[(size_t)k * 512 + colbase + cc]);
  }
  for (int it = 0; it < 128; ++it) {
    int idx = it * 64 + tid;
    int cc = idx & 15, k = idx >> 4;
    *(short*)(smem + wo1_off(cc, k)) = (cc < 8) ? f2bf(Wo1[(size_t)k * 256 + j * 8 + cc]) : (short)0;
  }

  const int lc = lane & 15;
  const int kl = (lane >> 4) * 8;        // frag k sub-offset (elements)
  const float bgu  = bg[colbase + lc];
  const float bgr  = bg[512 + colbase + lc];
  const float bhc  = bh[colbase + lc];
  const float bo1c = (lc < 8) ? bo1[j * 8 + lc] : 0.f;
  const float wo2c = (lc < 8) ? Wo2[j * 8 + lc] : 0.f;
  __syncthreads();

  // fragment-gather bases (row = rowbase + lc [+16], byte col offset = kl*2)
  const char* hfrag0  = (const char*)(hbf  + (size_t)(rowbase + lc) * HDIM + kl);
  const char* hfrag1  = hfrag0 + (size_t)16 * HDIM * 2;
  const char* rhfrag0 = (const char*)(rhbf + (size_t)(rowbase + lc) * HDIM + kl);
  const char* rhfrag1 = rhfrag0 + (size_t)16 * HDIM * 2;

  float hreg0[4] = {0,0,0,0}, hreg1[4] = {0,0,0,0};

  for (int t = 0; t < SEQ; ++t) {
    // ---- x A-frags for both M-tiles (fp32 load + cvt_pk) ----
    bf16x8 xa0[16], xa1[16];
    {
      const float* xr0 = x + ((size_t)(rowbase + lc) * SEQ + t) * IDIM + kl;
      const float* xr1 = xr0 + (size_t)16 * SEQ * IDIM;
#pragma unroll
      for (int ks = 0; ks < 16; ++ks) {
        float4 a = *(const float4*)(xr0 + ks * 32);
        float4 b = *(const float4*)(xr0 + ks * 32 + 4);
        u32x4 v = {cvtpk(a.x, a.y), cvtpk(a.z, a.w), cvtpk(b.x, b.y), cvtpk(b.z, b.w)};
        xa0[ks] = __builtin_bit_cast(bf16x8, v);
      }
#pragma unroll
      for (int ks = 0; ks < 16; ++ks) {
        float4 a = *(const float4*)(xr1 + ks * 32);
        float4 b = *(const float4*)(xr1 + ks * 32 + 4);
        u32x4 v = {cvtpk(a.x, a.y), cvtpk(a.z, a.w), cvtpk(b.x, b.y), cvtpk(b.z, b.w)};
        xa1[ks] = __builtin_bit_cast(bf16x8, v);
      }
    }
    // ---- gates-x MFMAs: B-frag loaded once, used by both M-tiles ----
    f32x4 gu0 = {0,0,0,0}, gu1 = {0,0,0,0}, gr0 = {0,0,0,0}, gr1 = {0,0,0,0};
#pragma unroll
    for (int ks = 0; ks < 16; ++ks) {
      bf16x8 bu = LDB(wgs_off(lc, ks * 32 + kl));
      bf16x8 br = LDB(wgs_off(16 + lc, ks * 32 + kl));
      gu0 = MFMA(xa0[ks], bu, gu0);
      gu1 = MFMA(xa1[ks], bu, gu1);
      gr0 = MFMA(xa0[ks], br, gr0);
      gr1 = MFMA(xa1[ks], br, gr1);
    }
    // ---- hop B: h_{t-1} ----
    i32x4 ha0[16], ha1[16];
    if (t) {
      poll32(fB, (uint32_t)t);
      GLD_BATCH16(ha0, hfrag0);
      GLD_BATCH16(ha1, hfrag1);
      GLD_FENCE();
#pragma unroll
      for (int ks = 0; ks < 16; ++ks) {
        bf16x8 bu = LDB(wgs_off(lc, 512 + ks * 32 + kl));
        bf16x8 br = LDB(wgs_off(16 + lc, 512 + ks * 32 + kl));
        gu0 = MFMA(asbf(ha0[ks]), bu, gu0);
        gu1 = MFMA(asbf(ha1[ks]), bu, gu1);
        gr0 = MFMA(asbf(ha0[ks]), br, gr0);
        gr1 = MFMA(asbf(ha1[ks]), br, gr1);
      }
    }
    float uv0[4], uv1[4], rhv0[4], rhv1[4];
#pragma unroll
    for (int ri = 0; ri < 4; ++ri) {
      uv0[ri]  = sigm(gu0[ri] + bgu);
      uv1[ri]  = sigm(gu1[ri] + bgu);
      rhv0[ri] = sigm(gr0[ri] + bgr) * hreg0[ri];
      rhv1[ri] = sigm(gr1[ri] + bgr) * hreg1[ri];
    }
    if (t) {   // rh(0)=0 group-wide: no publish/consume at t=0
      publish32x16(smem, rhbf, rowbase, colbase, lane, rhv0, rhv1);
      flag_pub(myA, (uint32_t)(t + 1));
    }
    // ---- fA shadow: head MFMAs (h_{t-1} in regs) + cand-x MFMAs ----
    f32x4 hd0 = {0,0,0,0}, hd1 = {0,0,0,0};
    if (t) {
#pragma unroll
      for (int ks = 0; ks < 16; ++ks) {
        bf16x8 bo = LDB(wo1_off(lc, ks * 32 + kl));
        hd0 = MFMA(asbf(ha0[ks]), bo, hd0);
        hd1 = MFMA(asbf(ha1[ks]), bo, hd1);
      }
    }
    f32x4 cx0 = {0,0,0,0}, cx1 = {0,0,0,0};
#pragma unroll
    for (int ks = 0; ks < 16; ++ks) {
      bf16x8 bc = LDB(whs_off(lc, ks * 32 + kl));
      cx0 = MFMA(xa0[ks], bc, cx0);
      cx1 = MFMA(xa1[ks], bc, cx1);
    }
    // ---- hop A: r*h ----
    if (t) {
      i32x4 ra0[16], ra1[16];
      poll32(fA, (uint32_t)(t + 1));
      GLD_BATCH16(ra0, rhfrag0);
      GLD_BATCH16(ra1, rhfrag1);
      GLD_FENCE();
#pragma unroll
      for (int ks = 0; ks < 16; ++ks) {
        bf16x8 bc = LDB(whs_off(lc, 512 + ks * 32 + kl));
        cx0 = MFMA(asbf(ra0[ks]), bc, cx0);
        cx1 = MFMA(asbf(ra1[ks]), bc, cx1);
      }
    }
    float hnv0[4], hnv1[4];
#pragma unroll
    for (int ri = 0; ri < 4; ++ri) {
      float c0 = tanhf(cx0[ri] + bhc);
      float c1 = tanhf(cx1[ri] + bhc);
      float h0 = hreg0[ri] + uv0[ri] * (c0 - hreg0[ri]);
      float h1 = hreg1[ri] + uv1[ri] * (c1 - hreg1[ri]);
      hreg0[ri] = h0; hreg1[ri] = h1; hnv0[ri] = h0; hnv1[ri] = h1;
      if (t == SEQ - 1) {
        int r0 = (lane >> 4) * 4 + ri;
        out[(size_t)(BATCH * SEQ) + (size_t)(rowbase + r0) * HDIM + colbase + lc] = h0;
        out[(size_t)(BATCH * SEQ) + (size_t)(rowbase + 16 + r0) * HDIM + colbase + lc] = h1;
      }
    }
    publish32x16(smem, hbf, rowbase, colbase, lane, hnv0, hnv1);
    flag_pub(myB, (uint32_t)(t + 1));
    // ---- finish head y_{t-1}; atomics after fB pub (off the drain path) ----
    if (t) {
#pragma unroll
      for (int ri = 0; ri < 4; ++ri) {
        float z0 = fmaxf(hd0[ri] + bo1c, 0.f) * wo2c;
        float z1 = fmaxf(hd1[ri] + bo1c, 0.f) * wo2c;
        z0 += __shfl_xor(z0, 1); z0 += __shfl_xor(z0, 2);
        z0 += __shfl_xor(z0, 4); z0 += __shfl_xor(z0, 8);
        z1 += __shfl_xor(z1, 1); z1 += __shfl_xor(z1, 2);
        z1 += __shfl_xor(z1, 4); z1 += __shfl_xor(z1, 8);
        if (lc == 0) {
          int r0 = rowbase + (lane >> 4) * 4 + ri;
          unsafeAtomicAdd(&out[(size_t)r0 * SEQ + (t - 1)], z0);
          unsafeAtomicAdd(&out[(size_t)(r0 + 16) * SEQ + (t - 1)], z1);
        }
      }
    }
  }
  // ---- epilogue: y_{SEQ-1} ----
  poll32(fB, (uint32_t)SEQ);
  i32x4 ha0[16], ha1[16];
  GLD_BATCH16(ha0, hfrag0);
  GLD_BATCH16(ha1, hfrag1);
  GLD_FENCE();
  f32x4 hd0 = {0,0,0,0}, hd1 = {0,0,0,0};
#pragma unroll
  for (int ks = 0; ks < 16; ++ks) {
    bf16x8 bo = LDB(wo1_off(lc, ks * 32 + kl));
    hd0 = MFMA(asbf(ha0[ks]), bo, hd0);
    hd1 = MFMA(asbf(ha1[ks]), bo, hd1);
  }
#pragma unroll
  for (int ri = 0; ri < 4; ++ri) {
    float z0 = fmaxf(hd0[ri] + bo1c, 0.f) * wo2c;
    float z1 = fmaxf(hd1[ri] + bo1c, 0.f) * wo2c;
    z0 += __shfl_xor(z0, 1); z0 += __shfl_xor(z0, 2);
    z0 += __shfl_xor(z0, 4); z0 += __shfl_xor(z0, 8);
    z1 += __shfl_xor(z1, 1); z1 += __shfl_xor(z1, 2);
    z1 += __shfl_xor(z1, 4); z1 += __shfl_xor(z1, 8);
    if (lc == 0) {
      int r0 = rowbase + (lane >> 4) * 4 + ri;
      unsafeAtomicAdd(&out[(size_t)r0 * SEQ + (SEQ - 1)], z0);
      unsafeAtomicAdd(&out[(size_t)(r0 + 16) * SEQ + (SEQ - 1)], z1);
    }
  }
}

extern "C" void kernel_launch(void* const* d_in, const int* in_sizes, int n_in,
                              void* d_out, int out_size, void* d_ws, size_t ws_size,
                              hipStream_t stream) {
  const float* x   = (const float*)d_in[0];
  const float* Wg  = (const float*)d_in[1];
  const float* bg  = (const float*)d_in[2];
  const float* Wh  = (const float*)d_in[3];
  const float* bh  = (const float*)d_in[4];
  const float* Wo1 = (const float*)d_in[5];
  const float* bo1 = (const float*)d_in[6];
  const float* Wo2 = (const float*)d_in[7];
  const float* bo2 = (const float*)d_in[8];
  float* out = (float*)d_out;
  char*  ws  = (char*)d_ws;
  if (ws_size < WS_NEEDED) return;

  hipMemsetAsync(ws, 0, WS_ZERO, stream);      // flag arrays
  init_ys_kernel<<<dim3(512), dim3(256), 0, stream>>>(out, bo2);

  (void)hipFuncSetAttribute((const void*)gru_persist,
                            hipFuncAttributeMaxDynamicSharedMemorySize, SMEM_BYTES);

  // 256 blocks x ~113KB LDS -> 1 block/CU, all co-resident (proven r2-r8).
  gru_persist<<<dim3(NG * WC), dim3(64), SMEM_BYTES, stream>>>(
      x, Wg, bg, Wh, bh, Wo1, bo1, Wo2, bo2, out, ws);
}

// Round 11
// 8293.993 us; speedup vs baseline: 1.6089x; 1.6089x over previous
//
#include <hip/hip_runtime.h>
#include <hip/hip_bf16.h>
#include <stdint.h>

typedef float f32x4 __attribute__((ext_vector_type(4)));
typedef short bf16x8 __attribute__((ext_vector_type(8)));
typedef int   i32x4  __attribute__((ext_vector_type(4)));
typedef unsigned int u32x4 __attribute__((ext_vector_type(4)));

#define DEVINL static __device__ __forceinline__

// ---------------- problem dims ----------------
constexpr int BATCH = 256, SEQ = 512, IDIM = 512, HDIM = 512;
constexpr int NG = 8, WC = 32, RPG = 32, CPW = 16;

// ---------------- LDS map (bytes) ----------------
constexpr int WGS_OFF = 0;        // Wg stripe [32 cols][1024 k] bf16 (64KB), XOR-swizzled
constexpr int WHS_OFF = 65536;    // Wh stripe [16 cols][1024 k] bf16 (32KB)
constexpr int WO1_OFF = 98304;    // Wo1 stripe [16 cols][512 k] bf16 (16KB, cols 8..15 zero)
constexpr int XPOSE_OFF = 114688; // 2 waves x 640B repack buffers
constexpr int SMEM_BYTES = XPOSE_OFF + 2 * 640;   // 115968

// ---------------- ws map (bytes) ----------------
// flags per group (512B region): fA u32[mt*32+j] at +0, fB at +256
constexpr size_t WS_ZERO = 4096;              // flag arrays (memset each call)
constexpr size_t HBF_OFF  = 8192;             // bf16 h   [256][512] (256KB), no init needed
constexpr size_t RHBF_OFF = HBF_OFF + 262144; // bf16 r*h [256][512] (256KB), no init needed
constexpr size_t WS_NEEDED = RHBF_OFF + 262144;

DEVINL short f2bf(float f) {
  uint32_t u = __float_as_uint(f);
  u += 0x7FFFu + ((u >> 16) & 1u);   // RNE
  return (short)(u >> 16);
}
DEVINL uint32_t cvtpk(float lo, float hi) {   // 2 bf16 in one instr (RNE) — r9-proven
  uint32_t r;
  asm("v_cvt_pk_bf16_f32 %0, %1, %2" : "=v"(r) : "v"(lo), "v"(hi));
  return r;
}
DEVINL int wgs_off(int c, int k) { return WGS_OFF + c * 2048 + ((k * 2) ^ ((c & 7) << 4)); }
DEVINL int whs_off(int c, int k) { return WHS_OFF + c * 2048 + ((k * 2) ^ ((c & 7) << 4)); }
DEVINL int wo1_off(int c, int k) { return WO1_OFF + c * 1024 + ((k * 2) ^ ((c & 7) << 4)); }
DEVINL float sigm(float v) { return 1.f / (1.f + __expf(-v)); }
DEVINL bf16x8 asbf(i32x4 v) { return __builtin_bit_cast(bf16x8, v); }

// ---------------- flag / exchange primitives (agent scope: sc1) — r8-proven ----------------
DEVINL void flag_pub(uint32_t* p, uint32_t v) {
  asm volatile("s_waitcnt vmcnt(0) lgkmcnt(0)\n\tglobal_store_dword %0, %1, off sc1"
               :: "v"(p), "v"(v) : "memory");
}
// poll own 32-slot region (2 cache lines). Throttled + bounded.
DEVINL void poll32(const uint32_t* base, uint32_t target) {
  const uint32_t* p = base + (threadIdx.x & 31);
  int iter = 0;
  for (;;) {
    uint32_t v;
    asm volatile("global_load_dword %0, %1, off sc1\n\ts_waitcnt vmcnt(0)"
                 : "=v"(v) : "v"(p) : "memory");
    if (__all((int)(v >= target))) break;
    if (++iter > 20000) break;           // bounded: pathology -> fast fail, not timeout
    __builtin_amdgcn_s_sleep(1);         // throttle the fabric read-storm
  }
  __builtin_amdgcn_sched_barrier(0);
}
// repack 16x16 bf16 tile through private LDS slice -> 8B/lane store (issue only)
DEVINL void publish16x16(char* smem, int xpose, short* dst, int grow, int colbase,
                         int lane, const float* vals) {
  const int q = lane >> 4, lc = lane & 15;
#pragma unroll
  for (int ri = 0; ri < 4; ++ri)
    *(short*)(smem + xpose + (q * 4 + ri) * 40 + lc * 2) = f2bf(vals[ri]);
  asm volatile("s_waitcnt lgkmcnt(0)" ::: "memory");
  __builtin_amdgcn_sched_barrier(0);
  const int rl = lane >> 2, cq = lane & 3;
  unsigned long long d = *(const unsigned long long*)(smem + xpose + rl * 40 + cq * 8);
  short* gp = dst + (size_t)(grow + rl) * HDIM + colbase + cq * 4;
  asm volatile("global_store_dwordx2 %0, %1, off sc1" :: "v"(gp), "v"(d) : "memory");
}
// exchange-fragment gathers (sc1) — 16 x 16B, one fence
#define GLD16(dst, ptr, imm) \
  asm volatile("global_load_dwordx4 %0, %1, off offset:" imm " sc1" : "=v"(dst) : "v"(ptr))
#define GLD_ALL16(arr, ptr) do { \
  GLD16(arr[0],  ptr, "0");   GLD16(arr[1],  ptr, "64");  \
  GLD16(arr[2],  ptr, "128"); GLD16(arr[3],  ptr, "192"); \
  GLD16(arr[4],  ptr, "256"); GLD16(arr[5],  ptr, "320"); \
  GLD16(arr[6],  ptr, "384"); GLD16(arr[7],  ptr, "448"); \
  GLD16(arr[8],  ptr, "512"); GLD16(arr[9],  ptr, "576"); \
  GLD16(arr[10], ptr, "640"); GLD16(arr[11], ptr, "704"); \
  GLD16(arr[12], ptr, "768"); GLD16(arr[13], ptr, "832"); \
  GLD16(arr[14], ptr, "896"); GLD16(arr[15], ptr, "960"); \
  asm volatile("s_waitcnt vmcnt(0)" ::: "memory"); \
  __builtin_amdgcn_sched_barrier(0); \
} while (0)

#define MFMA(a, b, c) __builtin_amdgcn_mfma_f32_16x16x32_bf16((a), (b), (c), 0, 0, 0)
#define LDB(off) (*(const bf16x8*)(smem + (off)))

// x(tt) -> bf16 A-frags (plain C loads; compiler schedules waits before cvts)
#define LOADCVT_X(tt) do { \
  const float* xr_ = x + ((size_t)(rowbase + arow) * SEQ + (size_t)(tt)) * IDIM + kl; \
  _Pragma("unroll") \
  for (int ks = 0; ks < 16; ++ks) { \
    float4 a_ = *(const float4*)(xr_ + ks * 32); \
    float4 b_ = *(const float4*)(xr_ + ks * 32 + 4); \
    u32x4 v_ = {cvtpk(a_.x, a_.y), cvtpk(a_.z, a_.w), \
                cvtpk(b_.x, b_.y), cvtpk(b_.z, b_.w)}; \
    xa[ks] = __builtin_bit_cast(bf16x8, v_); \
  } \
} while (0)
// gates-x MFMAs into loop-carried accumulators
#define GATES_X() do { \
  gu0 = (f32x4){0,0,0,0}; gu1 = (f32x4){0,0,0,0}; \
  gr0 = (f32x4){0,0,0,0}; gr1 = (f32x4){0,0,0,0}; \
  _Pragma("unroll") \
  for (int ks = 0; ks < 16; ks += 2) { \
    gu0 = MFMA(xa[ks],   LDB(wgs_off(lc, ks * 32 + kl)),            gu0); \
    gu1 = MFMA(xa[ks+1], LDB(wgs_off(lc, (ks + 1) * 32 + kl)),      gu1); \
    gr0 = MFMA(xa[ks],   LDB(wgs_off(16 + lc, ks * 32 + kl)),       gr0); \
    gr1 = MFMA(xa[ks+1], LDB(wgs_off(16 + lc, (ks + 1) * 32 + kl)), gr1); \
  } \
} while (0)

__global__ void __launch_bounds__(256, 1) init_ys_kernel(float* out, const float* bo2) {
  int i = blockIdx.x * 256 + threadIdx.x;
  if (i < BATCH * SEQ) out[i] = bo2[0];
}

__global__ void __launch_bounds__(128, 1) gru_persist(
    const float* __restrict__ x,  const float* __restrict__ Wg, const float* __restrict__ bg,
    const float* __restrict__ Wh, const float* __restrict__ bh,
    const float* __restrict__ Wo1,const float* __restrict__ bo1,
    const float* __restrict__ Wo2,const float* __restrict__ bo2,
    float* __restrict__ out, char* __restrict__ ws)
{
  extern __shared__ char smem[];
  const int bid  = blockIdx.x;
  const int gi   = bid & 7;        // group; bid&7 keeps group's x rows on one XCD L2 (perf-only)
  const int j    = bid >> 3;       // 0..31 within group
  const int tid  = threadIdx.x;
  const int lane = tid & 63;
  const int mt   = tid >> 6;       // wave 0,1 = M-tile
  const int rowbase = gi * RPG;
  const int colbase = j * CPW;

  short* hbf  = (short*)(ws + HBF_OFF);
  short* rhbf = (short*)(ws + RHBF_OFF);
  uint32_t* fA = (uint32_t*)(ws + (size_t)gi * 512);
  uint32_t* fB = (uint32_t*)(ws + (size_t)gi * 512 + 256);
  const uint32_t* fAmine = fA + mt * 32;   // this wave's producers (same mt-half)
  const uint32_t* fBmine = fB + mt * 32;
  uint32_t* myA = fA + (mt * 32 + j);
  uint32_t* myB = fB + (mt * 32 + j);

  // ---------------- init: weights -> LDS (128 threads, one-time) ----------------
  for (int it = 0; it < 256; ++it) {
    int cc = tid & 31;
    int k = (tid >> 5) + it * 4;
    int cg = (cc < 16) ? (colbase + cc) : (512 + colbase + (cc - 16));
    *(short*)(smem + wgs_off(cc, k)) = f2bf(Wg[(size_t)k * 1024 + cg]);
  }
  for (int it = 0; it < 128; ++it) {
    int cc = tid & 15;
    int k = (tid >> 4) + it * 8;
    *(short*)(smem + whs_off(cc, k)) = f2bf(Wh[(size_t)k * 512 + colbase + cc]);
  }
  for (int it = 0; it < 64; ++it) {
    int cc = tid & 15;
    int k = (tid >> 4) + it * 8;
    *(short*)(smem + wo1_off(cc, k)) = (cc < 8) ? f2bf(Wo1[(size_t)k * 256 + j * 8 + cc]) : (short)0;
  }

  const int lc = lane & 15;
  const float bgu  = bg[colbase + lc];
  const float bgr  = bg[512 + colbase + lc];
  const float bhc  = bh[colbase + lc];
  const float bo1c = (lc < 8) ? bo1[j * 8 + lc] : 0.f;
  const float wo2c = (lc < 8) ? Wo2[j * 8 + lc] : 0.f;
  __syncthreads();   // the ONLY block barrier

  const int arow  = mt * 16 + lc;          // A-frag row (local)
  const int kl    = (lane >> 4) * 8;       // frag k sub-offset (elements)
  const int xpose = XPOSE_OFF + mt * 640;
  const int grow  = rowbase + mt * 16;

  const char* hfrag  = (const char*)(hbf  + (size_t)(rowbase + arow) * HDIM + kl);
  const char* rhfrag = (const char*)(rhbf + (size_t)(rowbase + arow) * HDIM + kl);

  bf16x8 xa[16];                       // current-step A-frags
  f32x4 gu0, gu1, gr0, gr1;            // loop-carried gate accumulators

  // ---------------- prologue: x(0) convert + gates-x(0) ----------------
  LOADCVT_X(0);
  GATES_X();

  float hreg[4] = {0.f, 0.f, 0.f, 0.f};
  for (int t = 0; t < SEQ; ++t) {
    // ---- hop B: h_{t-1} -> finish gates ----
    i32x4 ha[16];
    if (t) {
      poll32(fBmine, (uint32_t)t);
      GLD_ALL16(ha, hfrag);
#pragma unroll
      for (int ks = 0; ks < 16; ks += 2) {
        gu0 = MFMA(asbf(ha[ks]),   LDB(wgs_off(lc, 512 + ks * 32 + kl)),            gu0);
        gu1 = MFMA(asbf(ha[ks+1]), LDB(wgs_off(lc, 512 + (ks + 1) * 32 + kl)),      gu1);
        gr0 = MFMA(asbf(ha[ks]),   LDB(wgs_off(16 + lc, 512 + ks * 32 + kl)),       gr0);
        gr1 = MFMA(asbf(ha[ks+1]), LDB(wgs_off(16 + lc, 512 + (ks + 1) * 32 + kl)), gr1);
      }
    }
    f32x4 gu = gu0 + gu1, gr = gr0 + gr1;
    float uv[4], rhv[4];
#pragma unroll
    for (int ri = 0; ri < 4; ++ri) {
      uv[ri]  = sigm(gu[ri] + bgu);
      rhv[ri] = sigm(gr[ri] + bgr) * hreg[ri];
    }
    // ---- publish rh (issue), SHADOW the drain with LDS-only MFMA work ----
    if (t) publish16x16(smem, xpose, rhbf, grow, colbase, lane, rhv);
    f32x4 hd0 = {0,0,0,0}, hd1 = {0,0,0,0};
    if (t) {
#pragma unroll
      for (int ks = 0; ks < 16; ks += 2) {
        hd0 = MFMA(asbf(ha[ks]),   LDB(wo1_off(lc, ks * 32 + kl)),       hd0);
        hd1 = MFMA(asbf(ha[ks+1]), LDB(wo1_off(lc, (ks + 1) * 32 + kl)), hd1);
      }
    }
    f32x4 cx0 = {0,0,0,0}, cx1 = {0,0,0,0};
#pragma unroll
    for (int ks = 0; ks < 16; ks += 2) {
      cx0 = MFMA(xa[ks],   LDB(whs_off(lc, ks * 32 + kl)),       cx0);
      cx1 = MFMA(xa[ks+1], LDB(whs_off(lc, (ks + 1) * 32 + kl)), cx1);
    }
    if (t) flag_pub(myA, (uint32_t)(t + 1));    // rh store drained during shadow
    // ---- hop A: r*h -> cand-h ----
    f32x4 ch0 = {0,0,0,0}, ch1 = {0,0,0,0};
    if (t) {
      poll32(fAmine, (uint32_t)(t + 1));
      i32x4 ra[16];
      GLD_ALL16(ra, rhfrag);
#pragma unroll
      for (int ks = 0; ks < 16; ks += 2) {
        ch0 = MFMA(asbf(ra[ks]),   LDB(whs_off(lc, 512 + ks * 32 + kl)),       ch0);
        ch1 = MFMA(asbf(ra[ks+1]), LDB(whs_off(lc, 512 + (ks + 1) * 32 + kl)), ch1);
      }
    }
    // ---- h update ----
    f32x4 cc = cx0 + cx1 + ch0 + ch1;
    float hnv[4];
#pragma unroll
    for (int ri = 0; ri < 4; ++ri) {
      float cand = tanhf(cc[ri] + bhc);
      float hnew = hreg[ri] + uv[ri] * (cand - hreg[ri]);
      hreg[ri] = hnew; hnv[ri] = hnew;
      if (t == SEQ - 1) {
        int row = mt * 16 + (lane >> 4) * 4 + ri;
        out[(size_t)(BATCH * SEQ) + (size_t)(rowbase + row) * HDIM + colbase + lc] = hnew;
      }
    }
    // ---- publish h (issue), SHADOW the drain: x(t+1) convert + gates-x(t+1) ----
    publish16x16(smem, xpose, hbf, grow, colbase, lane, hnv);
    if (t < SEQ - 1) {
      LOADCVT_X(t + 1);     // x loads consumed (waited) by cvts before flag's vmcnt(0)
      GATES_X();
    }
    flag_pub(myB, (uint32_t)(t + 1));           // h store drained during shadow
    // ---- finish head y_{t-1}: shuffles + atomics (off the drain path) ----
    if (t) {
      f32x4 d = hd0 + hd1;
#pragma unroll
      for (int ri = 0; ri < 4; ++ri) {
        float z = fmaxf(d[ri] + bo1c, 0.f) * wo2c;
        z += __shfl_xor(z, 1); z += __shfl_xor(z, 2);
        z += __shfl_xor(z, 4); z += __shfl_xor(z, 8);
        if (lc == 0) {
          int row = rowbase + mt * 16 + (lane >> 4) * 4 + ri;
          unsafeAtomicAdd(&out[(size_t)row * SEQ + (t - 1)], z);
        }
      }
    }
  }
  // ---- epilogue: y_{SEQ-1} ----
  poll32(fBmine, (uint32_t)SEQ);
  i32x4 ha[16];
  GLD_ALL16(ha, hfrag);
  f32x4 hd0 = {0,0,0,0}, hd1 = {0,0,0,0};
#pragma unroll
  for (int ks = 0; ks < 16; ks += 2) {
    hd0 = MFMA(asbf(ha[ks]),   LDB(wo1_off(lc, ks * 32 + kl)),       hd0);
    hd1 = MFMA(asbf(ha[ks+1]), LDB(wo1_off(lc, (ks + 1) * 32 + kl)), hd1);
  }
  f32x4 d = hd0 + hd1;
#pragma unroll
  for (int ri = 0; ri < 4; ++ri) {
    float z = fmaxf(d[ri] + bo1c, 0.f) * wo2c;
    z += __shfl_xor(z, 1); z += __shfl_xor(z, 2);
    z += __shfl_xor(z, 4); z += __shfl_xor(z, 8);
    if (lc == 0) {
      int row = rowbase + mt * 16 + (lane >> 4) * 4 + ri;
      unsafeAtomicAdd(&out[(size_t)row * SEQ + (SEQ - 1)], z);
    }
  }
}

extern "C" void kernel_launch(void* const* d_in, const int* in_sizes, int n_in,
                              void* d_out, int out_size, void* d_ws, size_t ws_size,
                              hipStream_t stream) {
  const float* x   = (const float*)d_in[0];
  const float* Wg  = (const float*)d_in[1];
  const float* bg  = (const float*)d_in[2];
  const float* Wh  = (const float*)d_in[3];
  const float* bh  = (const float*)d_in[4];
  const float* Wo1 = (const float*)d_in[5];
  const float* bo1 = (const float*)d_in[6];
  const float* Wo2 = (const float*)d_in[7];
  const float* bo2 = (const float*)d_in[8];
  float* out = (float*)d_out;
  char*  ws  = (char*)d_ws;
  if (ws_size < WS_NEEDED) return;

  hipMemsetAsync(ws, 0, WS_ZERO, stream);      // flag arrays
  init_ys_kernel<<<dim3(512), dim3(256), 0, stream>>>(out, bo2);

  (void)hipFuncSetAttribute((const void*)gru_persist,
                            hipFuncAttributeMaxDynamicSharedMemorySize, SMEM_BYTES);

  // 256 blocks x ~113KB LDS -> 1 block/CU, all co-resident (proven r2-r8).
  gru_persist<<<dim3(NG * WC), dim3(128), SMEM_BYTES, stream>>>(
      x, Wg, bg, Wh, bh, Wo1, bo1, Wo2, bo2, out, ws);
}